// Round 1
// baseline (122.231 us; speedup 1.0000x reference)
//
#include <hip/hip_runtime.h>

// B=32, C=128, H=W=32, kern=2 -> pooled h=w=16
// Fused: avgpool + var + z + pairwise Gaussian mixture log-densities + reduction.
// out = B * sum_{i,c,h,w} [ log(mean_j dA(i,j)+eps) - log(mean_j dB(i,j)+eps) ]
// d(i,j) = exp(-(z_i-mu_j)^2/(2 var_j)) / sqrt(var_j) = c1_j * exp2((z_i-mu_j)^2 * c2_j)
//   c1 = rsqrt(var), c2 = -log2(e)/(2 var)

#define GKL_EPS 1e-6f

__global__ __launch_bounds__(256) void gkl_main(
    const float* __restrict__ muA, const float* __restrict__ lvA,
    const float* __restrict__ muB, const float* __restrict__ lvB,
    const float* __restrict__ eps, double* __restrict__ ws)
{
    __shared__ float4 pab[2][32][16];  // [side][j][w] = {mu, c2, c1, pad}
    __shared__ float  zs[32][17];      // padded: bank-conflict-free column read
    __shared__ float  wsum[4];

    const int bid = blockIdx.x;        // 0..2047 = C*16
    const int c   = bid >> 4;
    const int h   = bid & 15;
    const int t   = threadIdx.x;
    const int w   = t & 15;
    const int b0  = t >> 4;            // 0..15

    const int row0 = 2 * h, col0 = 2 * w;

    // ---- Phase 1: pooled mixture params (each thread: 2 batch rows) ----
    #pragma unroll
    for (int rep = 0; rep < 2; ++rep) {
        const int b = b0 + rep * 16;
        const size_t base = ((size_t)(b * 128 + c) * 32 + row0) * 32 + col0;

        float2 m0 = *(const float2*)(muA + base);
        float2 m1 = *(const float2*)(muA + base + 32);
        float2 l0 = *(const float2*)(lvA + base);
        float2 l1 = *(const float2*)(lvA + base + 32);
        float mu  = (m0.x + m0.y + m1.x + m1.y) * 0.25f;
        float var = (__expf(l0.x) + __expf(l0.y) + __expf(l1.x) + __expf(l1.y)) * 0.0625f;
        float rsq = rsqrtf(var);
        float c2  = -0.7213475204444817f * rsq * rsq;   // -log2(e)/2 * (1/var)
        float ev  = eps[((b * 128 + c) * 16 + h) * 16 + w];
        float z   = fmaf(var * rsq, ev, mu);            // mu + sqrt(var)*eps
        pab[0][b][w] = make_float4(mu, c2, rsq, 0.f);
        zs[b][w] = z;

        float2 n0 = *(const float2*)(muB + base);
        float2 n1 = *(const float2*)(muB + base + 32);
        float2 k0 = *(const float2*)(lvB + base);
        float2 k1 = *(const float2*)(lvB + base + 32);
        float mub  = (n0.x + n0.y + n1.x + n1.y) * 0.25f;
        float varb = (__expf(k0.x) + __expf(k0.y) + __expf(k1.x) + __expf(k1.y)) * 0.0625f;
        float rsb  = rsqrtf(varb);
        pab[1][b][w] = make_float4(mub, -0.7213475204444817f * rsb * rsb, rsb, 0.f);
    }
    __syncthreads();

    // ---- Phase 2: wave-per-pixel pairwise loop ----
    const int lane = t & 63;
    const int wv   = t >> 6;           // wave 0..3
    const int i    = lane & 31;        // sample index
    const int side = lane >> 5;        // 0 = mixture A, 1 = mixture B
    const float4* __restrict__ P = &pab[side][0][0];

    float tot = 0.f;
    #pragma unroll
    for (int q = 0; q < 4; ++q) {
        const int p = wv * 4 + q;      // pixel (w coordinate) for this wave
        const float zi = zs[i][p];
        float acc = 0.f;
        #pragma unroll
        for (int j = 0; j < 32; ++j) {
            float4 f = P[j * 16 + p];  // wave-uniform per half -> LDS broadcast
            float d = zi - f.x;
            acc = fmaf(f.z, exp2f(d * d * f.y), acc);
        }
        float lg = __logf(acc * 0.03125f + GKL_EPS);
        tot += side ? -lg : lg;
    }

    #pragma unroll
    for (int o = 32; o; o >>= 1) tot += __shfl_xor(tot, o, 64);
    if (lane == 0) wsum[wv] = tot;
    __syncthreads();
    if (t == 0)
        ws[bid] = (double)wsum[0] + (double)wsum[1] + (double)wsum[2] + (double)wsum[3];
}

__global__ __launch_bounds__(256) void gkl_final(
    const double* __restrict__ ws, float* __restrict__ out)
{
    __shared__ double part[4];
    const int t = threadIdx.x;
    double s = 0.0;
    for (int k = t; k < 2048; k += 256) s += ws[k];
    #pragma unroll
    for (int o = 32; o; o >>= 1) s += __shfl_xor(s, o, 64);
    if ((t & 63) == 0) part[t >> 6] = s;
    __syncthreads();
    if (t == 0) out[0] = (float)(32.0 * (part[0] + part[1] + part[2] + part[3]));
}

extern "C" void kernel_launch(void* const* d_in, const int* in_sizes, int n_in,
                              void* d_out, int out_size, void* d_ws, size_t ws_size,
                              hipStream_t stream) {
    const float* muA = (const float*)d_in[0];
    const float* lvA = (const float*)d_in[1];
    const float* muB = (const float*)d_in[2];
    const float* lvB = (const float*)d_in[3];
    const float* ep  = (const float*)d_in[4];
    double* ws = (double*)d_ws;          // 2048 doubles = 16 KB
    float* out = (float*)d_out;

    gkl_main<<<2048, 256, 0, stream>>>(muA, lvA, muB, lvB, ep, ws);
    gkl_final<<<1, 256, 0, stream>>>(ws, out);
}